// Round 5
// baseline (223.337 us; speedup 1.0000x reference)
//
#include <hip/hip_runtime.h>

// HMM forward, chunk-parallel with warm-up ("forgetting") correction.
// B=64, T=4096, S=64.  C_CH=32 chunks of L=128 steps, WARM=24 warm-up steps.
//
// step(a + d) = step(a) + d (exact additive equivariance), so each chunk
// started from emis[t0] produces the true trajectory minus a scalar delta_c;
// deltas chain exactly via one boundary scalar per chunk + prefix sum.
//
// R4 lessons baked in:
//  - The register allocator lands at ~50-70 VGPRs under any occupancy hint
//    and spills a 64-deep Ecol (R0:48, R2:48, R4:68 regs => spilled). Fix by
//    CONSTRUCTION: split-K across 2 waves, 32 E-rows per wave (32 VGPRs).
//    Partials exchanged via double-buffered LDS, 1 barrier/step. Both waves
//    compute exp/log redundantly; s = p+q is commutative so their alphas
//    stay bit-identical.
//  - Phases B+C cost 108us (launch gaps + tiny kernel). Fused: phase A
//    writes per-chunk boundary & warm scalars to ws; each phase-C block
//    redundantly prefix-sums 32 deltas (reads ws only -- reading out[] for
//    boundaries would race with other blocks' corrections), then applies
//    its delta with float4 and block (b,C-1) emits log_Z.
//  - L=128 (warm overhead 24/128 vs 24/64): 13% less phase-A work.

#define BB 64
#define TT 4096
#define SS 64
#define C_CH 32          // chunks per batch
#define LL 128           // steps per chunk
#define WARM 24          // warm-up steps (init at t0 = LL*c - 25)

__device__ __forceinline__ float lane_bcast(float v, int l) {
    return __uint_as_float(__builtin_amdgcn_readlane(__float_as_uint(v), l));
}

// One recurrence step, split-K across 2 waves (W = wave id 0/1).
// Eh = E rows [32W, 32W+32) for this lane's column. pbuf[parity][wave][lane].
template <int W, bool WRITE>
__device__ __forceinline__ void step1(float& a, float e, int t,
                                      float* __restrict__ ob,
                                      const float (&Eh)[32],
                                      float (*pbuf)[2][64]) {
    const int lane = threadIdx.x & 63;
    float m = lane_bcast(a, 0);
    float u = __expf(a - m);

    float acc0 = 0.f, acc1 = 0.f, acc2 = 0.f, acc3 = 0.f;
    #pragma unroll
    for (int i = 0; i < 32; i += 4) {
        acc0 = __builtin_fmaf(lane_bcast(u, 32 * W + i + 0), Eh[i + 0], acc0);
        acc1 = __builtin_fmaf(lane_bcast(u, 32 * W + i + 1), Eh[i + 1], acc1);
        acc2 = __builtin_fmaf(lane_bcast(u, 32 * W + i + 2), Eh[i + 2], acc2);
        acc3 = __builtin_fmaf(lane_bcast(u, 32 * W + i + 3), Eh[i + 3], acc3);
    }
    float p = (acc0 + acc1) + (acc2 + acc3);

    const int par = t & 1;                 // double-buffer => 1 barrier/step
    pbuf[par][W][lane] = p;
    __syncthreads();
    float q = pbuf[par][1 - W][lane];
    float s = p + q;                       // commutative: identical in both waves

    a = m + __logf(s) + e;
    if (WRITE && W == 0) ob[t * SS + lane] = a;
}

template <int W, bool WRITE>
__device__ __forceinline__ void steps8(float& a, float (&ebuf)[8], int& t,
                                       const float* __restrict__ eb,
                                       float* __restrict__ ob,
                                       const float (&Eh)[32],
                                       float (*pbuf)[2][64]) {
    const int lane = threadIdx.x & 63;
    #pragma unroll
    for (int k = 0; k < 8; ++k) {
        float e  = ebuf[k];
        int   tp = (t + 8) & (TT - 1);     // 4096 wraps to 0 (valid dummy)
        ebuf[k]  = eb[tp * SS + lane];
        step1<W, WRITE>(a, e, t, ob, Eh, pbuf);
        ++t;
    }
}

template <int W>
__device__ __forceinline__ void steps_tail7(float& a, float (&ebuf)[8], int& t,
                                            float* __restrict__ ob,
                                            const float (&Eh)[32],
                                            float (*pbuf)[2][64]) {
    #pragma unroll
    for (int k = 0; k < 7; ++k) {
        step1<W, true>(a, ebuf[k], t, ob, Eh, pbuf);
        ++t;
    }
}

template <int W>
__device__ __forceinline__ void runA(int b, int c,
                                     const float* __restrict__ trans,
                                     const float* __restrict__ emis,
                                     float* __restrict__ out,
                                     float* __restrict__ ws_warm,
                                     float* __restrict__ ws_bound,
                                     float (*pbuf)[2][64]) {
    const int lane = threadIdx.x & 63;

    float Eh[32];                          // E rows [32W, 32W+32), column=lane
    #pragma unroll
    for (int i = 0; i < 32; ++i)
        Eh[i] = __expf(trans[(32 * W + i) * SS + lane]);

    const float* eb = emis + (size_t)b * TT * SS;
    float*       ob = out  + (size_t)b * TT * SS;
    float ebuf[8];

    if (c == 0) {
        float a = eb[lane];                // alpha[0] = emis[:,0,:]
        if (W == 0) ob[lane] = a;
        #pragma unroll
        for (int k = 0; k < 8; ++k) ebuf[k] = eb[(1 + k) * SS + lane];
        int t = 1;
        #pragma unroll 1
        for (int g = 0; g < 15; ++g)       // t = 1..120
            steps8<W, true>(a, ebuf, t, eb, ob, Eh, pbuf);
        steps_tail7<W>(a, ebuf, t, ob, Eh, pbuf);   // t = 121..127
        if (W == 0 && lane == 0) ws_bound[b * C_CH + 0] = a;
    } else {
        const int t0 = LL * c - (WARM + 1);
        float a = eb[t0 * SS + lane];      // pseudo-alpha at t0
        #pragma unroll
        for (int k = 0; k < 8; ++k) ebuf[k] = eb[(t0 + 1 + k) * SS + lane];
        int t = t0 + 1;
        #pragma unroll 1
        for (int g = 0; g < 3; ++g)        // 24 warm-up steps, no writes
            steps8<W, false>(a, ebuf, t, eb, ob, Eh, pbuf);
        if (W == 0 && lane == 0) ws_warm[b * C_CH + c] = a;  // t = LL*c - 1
        #pragma unroll 1
        for (int g = 0; g < 16; ++g)       // t = LL*c .. LL*c+127, write
            steps8<W, true>(a, ebuf, t, eb, ob, Eh, pbuf);
        if (W == 0 && lane == 0) ws_bound[b * C_CH + c] = a; // t = LL*(c+1)-1
    }
}

// 2 waves/block; ~60 VGPRs by construction. (4,4): cap 128 regs, 16 waves/CU.
__global__ __launch_bounds__(128)
__attribute__((amdgpu_waves_per_eu(4, 4)))
void hmm_phaseA(const float* __restrict__ trans,
                const float* __restrict__ emis,
                float* __restrict__ out,
                float* __restrict__ ws_warm,
                float* __restrict__ ws_bound) {
    __shared__ float pbuf[2][2][64];
    const int b = blockIdx.x, c = blockIdx.y;
    if ((threadIdx.x >> 6) == 0)
        runA<0>(b, c, trans, emis, out, ws_warm, ws_bound, pbuf);
    else
        runA<1>(b, c, trans, emis, out, ws_warm, ws_bound, pbuf);
}

// Fused correction: each block redundantly prefix-sums the 32 deltas from ws
// scalars (no out[] reads => no cross-block race), adds delta_c to its chunk,
// block (b, C-1) emits log_Z from the corrected last row.
__global__ __launch_bounds__(256)
void hmm_phaseC(float* __restrict__ out,
                const float* __restrict__ ws_warm,
                const float* __restrict__ ws_bound) {
    const int b = blockIdx.x, c = blockIdx.y, tid = threadIdx.x;
    __shared__ float sdelta;

    if (tid < 64) {
        float d = 0.f;
        if (tid > 0 && tid < C_CH)
            d = ws_bound[b * C_CH + tid - 1] - ws_warm[b * C_CH + tid];
        #pragma unroll
        for (int off = 1; off < C_CH; off <<= 1) {
            float v = __shfl_up(d, off, 64);
            if (tid >= off) d += v;
        }
        float dc = __shfl(d, c, 64);       // inclusive prefix at lane c
        if (tid == 0) sdelta = dc;
    }
    __syncthreads();
    const float delta = sdelta;

    float4* p4 = (float4*)(out + (size_t)b * TT * SS + (size_t)c * LL * SS);
    float4 last;
    #pragma unroll
    for (int i = 0; i < 8; ++i) {
        int idx = tid + 256 * i;           // 8*256 = 2048 float4 = LL*SS floats
        float4 v = p4[idx];
        v.x += delta; v.y += delta; v.z += delta; v.w += delta;
        p4[idx] = v;
        last = v;                          // i==7, tid 240..255 => row T-1
    }

    if (c == C_CH - 1 && tid >= 240) {
        // lanes 48..63 of wave 3 hold corrected alpha[T-1][:], 4 states each
        float mx = fmaxf(fmaxf(last.x, last.y), fmaxf(last.z, last.w));
        #pragma unroll
        for (int off = 8; off >= 1; off >>= 1)
            mx = fmaxf(mx, __shfl_xor(mx, off, 64));
        float sv = __expf(last.x - mx) + __expf(last.y - mx)
                 + __expf(last.z - mx) + __expf(last.w - mx);
        #pragma unroll
        for (int off = 8; off >= 1; off >>= 1)
            sv += __shfl_xor(sv, off, 64);
        if (tid == 240)
            out[(size_t)BB * TT * SS + b] = mx + __logf(sv);
    }
}

extern "C" void kernel_launch(void* const* d_in, const int* in_sizes, int n_in,
                              void* d_out, int out_size, void* d_ws, size_t ws_size,
                              hipStream_t stream) {
    const float* trans = (const float*)d_in[0];   // (S,S)
    const float* emis  = (const float*)d_in[1];   // (B,T,S)
    // d_in[2] = seq_lens — unused by the reference.
    float* out = (float*)d_out;                   // alpha (B,T,S) ++ log_Z (B,)

    float* ws_warm  = (float*)d_ws;               // B*C floats
    float* ws_bound = ws_warm + BB * C_CH;        // B*C floats

    hmm_phaseA<<<dim3(BB, C_CH), dim3(128), 0, stream>>>(trans, emis, out,
                                                         ws_warm, ws_bound);
    hmm_phaseC<<<dim3(BB, C_CH), dim3(256), 0, stream>>>(out, ws_warm, ws_bound);
}

// Round 6
// 166.324 us; speedup vs baseline: 1.3428x; 1.3428x over previous
//
#include <hip/hip_runtime.h>
#include <hip/hip_bf16.h>

// HMM forward, chunk-parallel + MFMA. B=64, T=4096, S=64.
// C_CH=64 chunks of LL=64, WARM=24 (R4-validated geometry).
//
// Phase A (MFMA): 256 waves; each wave owns 16 tasks (b fixed, c = 16*cg+n).
//   Per step, for all 16 tasks at once:
//     s[task][j] = sum_i exp(alpha[task][i] - M[task]) * E[i][j]
//   as D = A.B with A = E^T fragments (invariant, bf16, 32 VGPRs) and
//   B = u fragments rebuilt per step from D-layout alphas via cvt_pk_bf16 +
//   ds_bpermute (in-wave, no barrier). State alpha2 = alpha*log2(e) so
//   exp/log are raw v_exp_f32/v_log_f32.
//   Layouts (guide-verified): A[m=lane&15][k=(lane>>4)*8+e]; D: col=lane&15
//   (= task), row=(lane>>4)*4+reg (j = 16*jt + 4*q + reg).
//   c=0 runs the same 88-step schedule with t0=-25 (reads wrapped via &4095,
//   garbage warm); at s==25 its lanes override alpha := true alpha0=emis[0],
//   so its writes t=0..63 are exact and perfectly aligned with c>=1 chunks.
// Phase C: delta prefix-sum (from ws scalars) + float4 RMW correction + log_Z.

#define BB 64
#define TT 4096
#define SS 64
#define C_CH 64
#define LL 64
#define WARM 24

typedef __attribute__((ext_vector_type(8))) short short8;
typedef __attribute__((ext_vector_type(4))) float f32x4;

#define LOG2E 1.44269504088896340736f
#define LN2F  0.69314718055994530942f

__device__ __forceinline__ float fexp2(float x) {
#if __has_builtin(__builtin_amdgcn_exp2f)
    return __builtin_amdgcn_exp2f(x);
#else
    return exp2f(x);
#endif
}
__device__ __forceinline__ float flog2(float x) {
#if __has_builtin(__builtin_amdgcn_logf)
    return __builtin_amdgcn_logf(x);
#else
    return log2f(x);
#endif
}
__device__ __forceinline__ float bpermf(int idx, float v) {
    return __uint_as_float((unsigned)__builtin_amdgcn_ds_bpermute(idx, (int)__float_as_uint(v)));
}
__device__ __forceinline__ int pack_bf16(float x, float y) {
    __hip_bfloat162 h = __float22bfloat162_rn(make_float2(x, y));
    int r; __builtin_memcpy(&r, &h, 4); return r;
}
union PB { int i[4]; short8 v; };

// One recurrence step for 16 tasks. al2[jt] holds alpha2 at j=16*jt+4*q+r.
// er[jt] = emis[t][16*jt+4*q .. +3] (natural scale).
__device__ __forceinline__ void do_step(f32x4 (&al2)[4], const f32x4 (&er)[4],
                                        const short8 (&Af)[4][2],
                                        int idxM, int idx0, int idx1, int q) {
    // Per-task shift proxy: alpha2[task][0], held by lane n (q=0), reg D0.x.
    float M2 = bpermf(idxM, al2[0].x);

    // u = exp2(alpha2 - M2), packed to bf16 pairs (j even/odd adjacent).
    int pkk[4][2];
    #pragma unroll
    for (int jt = 0; jt < 4; ++jt) {
        float ux = fexp2(al2[jt].x - M2);
        float uy = fexp2(al2[jt].y - M2);
        float uz = fexp2(al2[jt].z - M2);
        float uw = fexp2(al2[jt].w - M2);
        pkk[jt][0] = pack_bf16(ux, uy);   // j = 16jt+4q+{0,1}
        pkk[jt][1] = pack_bf16(uz, uw);   // j = 16jt+4q+{2,3}
    }

    // Assemble B-fragments: lane needs u[task n][i], i = 32*kh + 8*q + e.
    // Source of pair p (=e>>1): lane n + 16*((2q + (p>>1))&3), its packed reg
    // (jt_src = 2*kh + (q>>1), h = p&1). jt_src's q-dependence => 2 bpermutes
    // + cndmask by q.
    short8 Bf[2];
    #pragma unroll
    for (int kh = 0; kh < 2; ++kh) {
        PB pb;
        #pragma unroll
        for (int p = 0; p < 4; ++p) {
            int idx = (p >> 1) ? idx1 : idx0;
            int lo = __builtin_amdgcn_ds_bpermute(idx, pkk[2 * kh + 0][p & 1]);
            int hi = __builtin_amdgcn_ds_bpermute(idx, pkk[2 * kh + 1][p & 1]);
            pb.i[p] = (q >= 2) ? hi : lo;
        }
        Bf[kh] = pb.v;
    }

    // s = u . E via MFMA, then alpha2' = (M2 + e*log2e) + log2(s).
    #pragma unroll
    for (int jt = 0; jt < 4; ++jt) {
        f32x4 d = {0.f, 0.f, 0.f, 0.f};
        d = __builtin_amdgcn_mfma_f32_16x16x32_bf16(Af[jt][0], Bf[0], d, 0, 0, 0);
        d = __builtin_amdgcn_mfma_f32_16x16x32_bf16(Af[jt][1], Bf[1], d, 0, 0, 0);
        al2[jt].x = fmaf(er[jt].x, LOG2E, M2) + flog2(d.x);
        al2[jt].y = fmaf(er[jt].y, LOG2E, M2) + flog2(d.y);
        al2[jt].z = fmaf(er[jt].z, LOG2E, M2) + flog2(d.z);
        al2[jt].w = fmaf(er[jt].w, LOG2E, M2) + flog2(d.w);
    }
}

__device__ __forceinline__ void load_row(f32x4 (&dst)[4],
                                         const float* __restrict__ eb,
                                         int t, int off) {
    const float* p = eb + (t & (TT - 1)) * SS + off;
    #pragma unroll
    for (int jt = 0; jt < 4; ++jt)
        dst[jt] = *(const f32x4*)(p + 16 * jt);
}

__global__ __launch_bounds__(64)
__attribute__((amdgpu_waves_per_eu(1, 1)))
void hmm_phaseA(const float* __restrict__ trans,
                const float* __restrict__ emis,
                float* __restrict__ out,
                float* __restrict__ ws_warm,
                float* __restrict__ ws_bound) {
    const int lane = threadIdx.x;
    const int n = lane & 15, q = lane >> 4;
    const int w = blockIdx.x;                  // 0..255
    const int b = w >> 2, cg = w & 3;
    const int c = 16 * cg + n;                 // this lane's task
    const bool is_c0 = (c == 0);
    const int off = 4 * q;

    // A-fragments: A[m=n][k] = E[k][16*jt+n], k = 32*kh + 8*q + e.
    short8 Af[4][2];
    #pragma unroll
    for (int jt = 0; jt < 4; ++jt)
        #pragma unroll
        for (int kh = 0; kh < 2; ++kh) {
            PB pb;
            #pragma unroll
            for (int p = 0; p < 4; ++p) {
                float v0 = __expf(trans[(32 * kh + 8 * q + 2 * p    ) * SS + 16 * jt + n]);
                float v1 = __expf(trans[(32 * kh + 8 * q + 2 * p + 1) * SS + 16 * jt + n]);
                pb.i[p] = pack_bf16(v0, v1);
            }
            Af[jt][kh] = pb.v;
        }

    const int idxM = n << 2;
    const int idx0 = ((n + 16 * ((2 * q + 0) & 3)) & 63) << 2;
    const int idx1 = ((n + 16 * ((2 * q + 1) & 3)) & 63) << 2;

    const float* eb = emis + (size_t)b * TT * SS;
    float*       ob = out  + (size_t)b * TT * SS;

    const int t0 = LL * c - (WARM + 1);        // c=0 => -25 (wrapped reads)

    // Init: alpha2 = emis[t0]*log2e (pseudo); keep row 0 for the c0 override.
    f32x4 al2[4], e0[4], ebuf[4][4];
    load_row(al2, eb, t0, off);
    #pragma unroll
    for (int jt = 0; jt < 4; ++jt) al2[jt] = al2[jt] * LOG2E;
    load_row(e0, eb, 0, off);
    #pragma unroll
    for (int k = 0; k < 4; ++k) load_row(ebuf[k], eb, t0 + 1 + k, off);

    // Warm-up: s = 1..24, no stores.
    #pragma unroll 1
    for (int g = 0; g < 6; ++g) {
        #pragma unroll
        for (int k = 0; k < 4; ++k) {
            int s = 4 * g + k + 1;
            f32x4 er[4];
            #pragma unroll
            for (int jt = 0; jt < 4; ++jt) er[jt] = ebuf[k][jt];
            load_row(ebuf[k], eb, t0 + s + 4, off);
            do_step(al2, er, Af, idxM, idx0, idx1, q);
        }
    }
    // Boundary (uncorrected) alpha at t = 64c-1: lane n (q=0) holds j=0.
    if (lane < 16)
        ws_warm[b * C_CH + 16 * cg + lane] = al2[0].x * LN2F;

    // Main: s = 25..88, writes t = t0+s = 64c .. 64c+63.
    #pragma unroll 1
    for (int g = 0; g < 16; ++g) {
        #pragma unroll
        for (int k = 0; k < 4; ++k) {
            int s = 25 + 4 * g + k;
            f32x4 er[4];
            #pragma unroll
            for (int jt = 0; jt < 4; ++jt) er[jt] = ebuf[k][jt];
            load_row(ebuf[k], eb, t0 + s + 4, off);
            do_step(al2, er, Af, idxM, idx0, idx1, q);
            if (k == 0 && g == 0 && is_c0) {
                // chunk 0: replace garbage warm result with true alpha0.
                #pragma unroll
                for (int jt = 0; jt < 4; ++jt) al2[jt] = e0[jt] * LOG2E;
            }
            float* p = ob + (t0 + s) * SS + off;
            #pragma unroll
            for (int jt = 0; jt < 4; ++jt)
                *(f32x4*)(p + 16 * jt) = al2[jt] * LN2F;
        }
    }
    if (lane < 16)
        ws_bound[b * C_CH + 16 * cg + lane] = al2[0].x * LN2F;
}

// Correction: redundant per-block prefix sum of deltas (ws scalars only),
// float4 RMW of the chunk, block (b, C-1) emits log_Z.
__global__ __launch_bounds__(256)
void hmm_phaseC(float* __restrict__ out,
                const float* __restrict__ ws_warm,
                const float* __restrict__ ws_bound) {
    const int b = blockIdx.x, c = blockIdx.y, tid = threadIdx.x;
    __shared__ float sdelta;

    if (tid < 64) {
        float d = 0.f;
        if (tid > 0 && tid < C_CH)
            d = ws_bound[b * C_CH + tid - 1] - ws_warm[b * C_CH + tid];
        #pragma unroll
        for (int off = 1; off < C_CH; off <<= 1) {
            float v = __shfl_up(d, off, 64);
            if (tid >= off) d += v;
        }
        float dc = __shfl(d, c, 64);
        if (tid == 0) sdelta = dc;
    }
    __syncthreads();
    const float delta = sdelta;

    float4* p4 = (float4*)(out + (size_t)b * TT * SS + (size_t)c * LL * SS);
    float4 last;
    #pragma unroll
    for (int i = 0; i < 4; ++i) {
        int idx = tid + 256 * i;               // 4*256 = 1024 float4 = LL*SS
        float4 v = p4[idx];
        v.x += delta; v.y += delta; v.z += delta; v.w += delta;
        p4[idx] = v;
        last = v;                              // i==3, tid 240..255 => row T-1
    }

    if (c == C_CH - 1 && tid >= 240) {
        float mx = fmaxf(fmaxf(last.x, last.y), fmaxf(last.z, last.w));
        #pragma unroll
        for (int off = 8; off >= 1; off >>= 1)
            mx = fmaxf(mx, __shfl_xor(mx, off, 64));
        float sv = __expf(last.x - mx) + __expf(last.y - mx)
                 + __expf(last.z - mx) + __expf(last.w - mx);
        #pragma unroll
        for (int off = 8; off >= 1; off >>= 1)
            sv += __shfl_xor(sv, off, 64);
        if (tid == 240)
            out[(size_t)BB * TT * SS + b] = mx + __logf(sv);
    }
}

extern "C" void kernel_launch(void* const* d_in, const int* in_sizes, int n_in,
                              void* d_out, int out_size, void* d_ws, size_t ws_size,
                              hipStream_t stream) {
    const float* trans = (const float*)d_in[0];   // (S,S)
    const float* emis  = (const float*)d_in[1];   // (B,T,S)
    // d_in[2] = seq_lens — unused by the reference.
    float* out = (float*)d_out;                   // alpha (B,T,S) ++ log_Z (B,)

    float* ws_warm  = (float*)d_ws;               // B*C floats
    float* ws_bound = ws_warm + BB * C_CH;        // B*C floats

    hmm_phaseA<<<dim3(BB * 4), dim3(64), 0, stream>>>(trans, emis, out,
                                                      ws_warm, ws_bound);
    hmm_phaseC<<<dim3(BB, C_CH), dim3(256), 0, stream>>>(out, ws_warm, ws_bound);
}